// Round 12
// baseline (5383.404 us; speedup 1.0000x reference)
//
#include <hip/hip_runtime.h>
#include <hip/hip_bf16.h>

#define BATCH 128
#define SEQ   1024
#define INDIM 256
#define HID   1024
#define NGATE 4096   // 4*HID
#define KTOT  1280   // INDIM + HID
#define OUTD  256
#define NKK   40     // total K-steps of 32 (1280/32)
#define XKK   8      // k-steps covering the x part (256/32)
#define HKK   32     // k-steps covering the h part
#define NBG   8      // batch groups
#define ROWS  16     // batch rows per group
#define NSL   32     // WGs per group
#define JCOLS 32     // h-columns per WG

typedef __attribute__((ext_vector_type(8))) short s16x8;
typedef __attribute__((ext_vector_type(4))) float f32x4;

__device__ __forceinline__ unsigned short f2bf(float f) {
    unsigned int u = __float_as_uint(f);
    u += 0x7FFFu + ((u >> 16) & 1u);
    return (unsigned short)(u >> 16);
}
__device__ __forceinline__ float sigmoidf_(float x) {
    return 1.0f / (1.0f + __expf(-x));
}
__device__ __forceinline__ float tanhf_(float x) {
    return 1.0f - 2.0f / (1.0f + __expf(2.0f * x));
}

// ---------------------------------------------------------------------------
// Prep 1: WT[n][k] bf16 (transposed, concatenated [Wx;Wh])
// ---------------------------------------------------------------------------
__global__ __launch_bounds__(256) void prep_wt(const float* __restrict__ Wx,
                                               const float* __restrict__ Wh,
                                               unsigned short* __restrict__ WT) {
    __shared__ float tile[64][65];
    int k0 = blockIdx.x * 64;
    int n0 = blockIdx.y * 64;
    for (int idx = threadIdx.x; idx < 64 * 64; idx += 256) {
        int kk = idx >> 6, nn = idx & 63;
        int k = k0 + kk;
        float v = (k < INDIM) ? Wx[(size_t)k * NGATE + (n0 + nn)]
                              : Wh[(size_t)(k - INDIM) * NGATE + (n0 + nn)];
        tile[kk][nn] = v;
    }
    __syncthreads();
    for (int idx = threadIdx.x; idx < 64 * 64; idx += 256) {
        int nn = idx >> 6, kk = idx & 63;
        WT[(size_t)(n0 + nn) * KTOT + (k0 + kk)] = f2bf(tile[kk][nn]);
    }
}

// ---------------------------------------------------------------------------
// Prep 2: x fp32 -> bf16, zero h0, zero per-wave flags (256 WG x 8 x 16)
// ---------------------------------------------------------------------------
__global__ __launch_bounds__(256) void prep_x(const float* __restrict__ x,
                                              unsigned short* __restrict__ xb,
                                              unsigned short* __restrict__ h0,
                                              unsigned int* __restrict__ flags) {
    int gid = blockIdx.x * blockDim.x + threadIdx.x;
    int stride = gridDim.x * blockDim.x;
    const int N4 = BATCH * SEQ * INDIM / 4;
    const float4* xv = reinterpret_cast<const float4*>(x);
    uint2* xo = reinterpret_cast<uint2*>(xb);
    for (int i = gid; i < N4; i += stride) {
        float4 v = xv[i];
        uint2 o;
        o.x = (unsigned)f2bf(v.x) | ((unsigned)f2bf(v.y) << 16);
        o.y = (unsigned)f2bf(v.z) | ((unsigned)f2bf(v.w) << 16);
        xo[i] = o;
    }
    const int NH = BATCH * HID;
    for (int i = gid; i < NH; i += stride) h0[i] = 0;
    for (int i = gid; i < 32768; i += stride) flags[i] = 0;
}

// ---------------------------------------------------------------------------
// Persistent LSTM (r10 geometry/layout verbatim; latency chain shortened).
// 256 WGs x 256 thr; WG=(bg,ns): rows bg*16..+16, h-cols ns*32..+32, 4 gates.
// Step order: poll(all waves) -> issue h loads -> x-MFMA (hides h latency)
// -> stage x(t+1) -> scatter h -> B2 -> h-MFMA -> gex -> B3 -> epilogue
// -> per-wave vmcnt drain + per-wave flag.  2 barriers/step (was 4).
// Sync primitives all r3/r6-proven: relaxed agent atomics, 64B-padded flags.
// ---------------------------------------------------------------------------
__global__ __launch_bounds__(256, 1) void lstm_persist(
    const unsigned short* __restrict__ xb,   // [B][S][INDIM] bf16
    const unsigned short* __restrict__ WT,   // [NGATE][KTOT] bf16
    unsigned short* __restrict__ h0,         // [B][HID] bf16 (zeroed)
    unsigned short* __restrict__ h1,         // [B][HID] bf16
    unsigned int* __restrict__ flags,        // [256 WG x 4 waves] x 16 uints
    const float* __restrict__ bias) {        // [NGATE]

    __shared__ unsigned short xbuf[2][XKK * 512];  // 2 x 8 KB, swizzled slots
    __shared__ unsigned short hbuf[HKK * 512];     // 32 KB, swizzled slots
    __shared__ float gex[4 * ROWS * JCOLS];        // 8 KB

    const int tid  = threadIdx.x;
    const int wave = tid >> 6, lane = tid & 63;
    const int lr = lane & 15, kq = lane >> 4;
    const int bg = blockIdx.x & 7;
    const int ns = blockIdx.x >> 3;
    const int b0 = bg * ROWS;
    const int j0 = ns * JCOLS;

    // ---- B fragments (gate=wave, cols j0..j0+31, full K); compiler will
    //      remat-stream most of these from L2 each step (known, accepted) ----
    s16x8 b0r[NKK], b1r[NKK];
    {
        const unsigned short* base0 =
            WT + ((size_t)(wave * HID + j0 + lr)) * KTOT + kq * 8;
        const unsigned short* base1 = base0 + (size_t)16 * KTOT;
#pragma unroll
        for (int kk = 0; kk < NKK; kk++) {
            b0r[kk] = *reinterpret_cast<const s16x8*>(base0 + kk * 32);
            b1r[kk] = *reinterpret_cast<const s16x8*>(base1 + kk * 32);
        }
    }

    // ---- epilogue constants ----
    const int ecol = tid & 31, erow0 = tid >> 5, erow1 = erow0 + 8;
    const int j = j0 + ecol;
    const float bf = bias[0 * HID + j], bi = bias[1 * HID + j],
                bgg = bias[2 * HID + j], bo = bias[3 * HID + j];
    float c0 = 0.f, c1 = 0.f;

    // ---- staging addressing ----
    const int srow = lane >> 2;
    const int skq = ((lane & 3) - ((lane >> 3) & 3)) & 3;
    const unsigned short* xsrc =
        xb + (size_t)(b0 + srow) * SEQ * INDIM + skq * 8;
    const int p_l = lr * 4 + ((kq + (lr >> 1)) & 3);

    // ---- flags: per-wave.  mine; and the 2 poll targets for this lane
    //      (producer = lane&31, waves (lane>>5) and (lane>>5)+2) ----
    unsigned int* wflag =
        flags + ((size_t)(bg * NSL + ns) * 4 + wave) * 16;
    const unsigned int* fpA =
        flags + ((size_t)(bg * NSL + (lane & 31)) * 4 + (lane >> 5)) * 16;
    const unsigned int* fpB = fpA + 2 * 16;

    // ---- prologue: stage x for t=0 ----
#pragma unroll
    for (int q = 0; q < 2; q++) {
        int kk = 2 * wave + q;
        __builtin_amdgcn_global_load_lds(
            (const __attribute__((address_space(1))) void*)(xsrc + (size_t)kk * 32),
            (__attribute__((address_space(3))) void*)(&xbuf[0][kk * 512]),
            16, 0, 0);
    }
    __syncthreads();

    for (int t = 0; t < SEQ; t++) {
        const unsigned short* hin = (t & 1) ? h1 : h0;
        unsigned short* hout      = (t & 1) ? h0 : h1;
        const int par = t & 1;

        // ---- 1. poll: every wave independently waits for all 32 producers
        //      x 4 waves (64 lanes x 2 flags). No barrier needed after. ----
        if (t > 0) {
            for (;;) {
                unsigned a = __hip_atomic_load(fpA, __ATOMIC_RELAXED,
                                               __HIP_MEMORY_SCOPE_AGENT);
                unsigned b = __hip_atomic_load(fpB, __ATOMIC_RELAXED,
                                               __HIP_MEMORY_SCOPE_AGENT);
                if (__all((int)(a >= (unsigned)t) & (int)(b >= (unsigned)t)))
                    break;
                __builtin_amdgcn_s_sleep(1);
            }
        }

        // ---- 2. issue h loads (16 x 8B per thread, L3) ----
        unsigned long long hv[16];
#pragma unroll
        for (int i = 0; i < 16; i++) {
            int u = tid + 256 * i;
            int kkh = u >> 7, v = u & 127, row = v >> 3, k8 = v & 7;
            const unsigned long long* gp = (const unsigned long long*)
                (hin + (size_t)(b0 + row) * HID + kkh * 32 + k8 * 4);
            hv[i] = __hip_atomic_load(gp, __ATOMIC_RELAXED,
                                      __HIP_MEMORY_SCOPE_AGENT);
        }

        // ---- 3. x-part MFMA (overlaps the in-flight h loads) ----
        f32x4 acc0 = {0.f, 0.f, 0.f, 0.f};
        f32x4 acc1 = {0.f, 0.f, 0.f, 0.f};
        {
            const unsigned short* ax = &xbuf[par][p_l * 8];
#pragma unroll
            for (int kk = 0; kk < XKK; kk++) {
                s16x8 a = *reinterpret_cast<const s16x8*>(ax + kk * 512);
                acc0 = __builtin_amdgcn_mfma_f32_16x16x32_bf16(a, b0r[kk], acc0, 0, 0, 0);
                acc1 = __builtin_amdgcn_mfma_f32_16x16x32_bf16(a, b1r[kk], acc1, 0, 0, 0);
            }
        }

        // ---- 4. fire-and-forget: stage x for t+1 ----
        if (t + 1 < SEQ) {
#pragma unroll
            for (int q = 0; q < 2; q++) {
                int kk = 2 * wave + q;
                __builtin_amdgcn_global_load_lds(
                    (const __attribute__((address_space(1))) void*)(xsrc + (size_t)(t + 1) * INDIM + kk * 32),
                    (__attribute__((address_space(3))) void*)(&xbuf[par ^ 1][kk * 512]),
                    16, 0, 0);
            }
        }

        // ---- 5. scatter h to swizzled LDS slots ----
#pragma unroll
        for (int i = 0; i < 16; i++) {
            int u = tid + 256 * i;
            int kkh = u >> 7, v = u & 127, row = v >> 3, k8 = v & 7;
            int kqh = k8 >> 1;
            int p = row * 4 + ((kqh + (row >> 1)) & 3);
            *(unsigned long long*)((char*)hbuf + kkh * 1024 + p * 16 + (k8 & 1) * 8) = hv[i];
        }
        __syncthreads();   // B2: hbuf ready (also fences prior-step gex reads)

        // ---- 6. h-part MFMA ----
        {
            const unsigned short* ah = &hbuf[p_l * 8];
#pragma unroll
            for (int kk = 0; kk < HKK; kk++) {
                s16x8 a = *reinterpret_cast<const s16x8*>(ah + kk * 512);
                acc0 = __builtin_amdgcn_mfma_f32_16x16x32_bf16(a, b0r[XKK + kk], acc0, 0, 0, 0);
                acc1 = __builtin_amdgcn_mfma_f32_16x16x32_bf16(a, b1r[XKK + kk], acc1, 0, 0, 0);
            }
        }

        // ---- 7. gate exchange (C/D: col=lane&15, row=(lane>>4)*4+r) ----
#pragma unroll
        for (int r = 0; r < 4; r++) {
            int row = kq * 4 + r;
            gex[wave * 512 + row * 32 + lr]      = acc0[r];
            gex[wave * 512 + row * 32 + 16 + lr] = acc1[r];
        }
        __syncthreads();   // B3: gex ready (also fences hbuf reads vs next scatter)

        // ---- 8. activations + c update + h stores ----
        {
            float ff = sigmoidf_(gex[0 * 512 + erow0 * 32 + ecol] + bf);
            float ii = sigmoidf_(gex[1 * 512 + erow0 * 32 + ecol] + bi);
            float gg = tanhf_(gex[2 * 512 + erow0 * 32 + ecol] + bgg);
            float oo = sigmoidf_(gex[3 * 512 + erow0 * 32 + ecol] + bo);
            c0 = ff * c0 + ii * gg;
            __hip_atomic_store(hout + (size_t)(b0 + erow0) * HID + j,
                               f2bf(oo * tanhf_(c0)),
                               __ATOMIC_RELAXED, __HIP_MEMORY_SCOPE_AGENT);
        }
        {
            float ff = sigmoidf_(gex[0 * 512 + erow1 * 32 + ecol] + bf);
            float ii = sigmoidf_(gex[1 * 512 + erow1 * 32 + ecol] + bi);
            float gg = tanhf_(gex[2 * 512 + erow1 * 32 + ecol] + bgg);
            float oo = sigmoidf_(gex[3 * 512 + erow1 * 32 + ecol] + bo);
            c1 = ff * c1 + ii * gg;
            __hip_atomic_store(hout + (size_t)(b0 + erow1) * HID + j,
                               f2bf(oo * tanhf_(c1)),
                               __ATOMIC_RELAXED, __HIP_MEMORY_SCOPE_AGENT);
        }

        // ---- 9. per-wave publish: drain own stores, store own flag ----
        asm volatile("s_waitcnt vmcnt(0)" ::: "memory");
        if (lane == 0)
            __hip_atomic_store(wflag, (unsigned)(t + 1),
                               __ATOMIC_RELAXED, __HIP_MEMORY_SCOPE_AGENT);
    }
}

// ---------------------------------------------------------------------------
// Final FC
// ---------------------------------------------------------------------------
__global__ __launch_bounds__(256) void final_fc(const unsigned short* __restrict__ h,
                                                const float* __restrict__ Wfc,
                                                const float* __restrict__ bfc,
                                                float* __restrict__ out) {
    int b = blockIdx.x;
    int o = threadIdx.x;
    const unsigned short* hr = h + (size_t)b * HID;
    float acc = bfc[o];
#pragma unroll 8
    for (int k = 0; k < HID; k++) {
        acc += __uint_as_float(((unsigned)hr[k]) << 16) * Wfc[(size_t)k * OUTD + o];
    }
    out[(size_t)b * OUTD + o] = acc;
}

// ---------------------------------------------------------------------------
extern "C" void kernel_launch(void* const* d_in, const int* in_sizes, int n_in,
                              void* d_out, int out_size, void* d_ws, size_t ws_size,
                              hipStream_t stream) {
    const float* x    = (const float*)d_in[0];
    const float* Wx   = (const float*)d_in[1];
    const float* Wh   = (const float*)d_in[2];
    const float* bias = (const float*)d_in[3];
    const float* Wfc  = (const float*)d_in[4];
    const float* bfc  = (const float*)d_in[5];
    float* out = (float*)d_out;

    char* ws = (char*)d_ws;
    // ws layout (bytes):
    //   WT    : 4096*1280*2    = 10,485,760  @ 0
    //   xb    : 128*1024*256*2 = 67,108,864  @ 10,485,760
    //   h0    : 128*1024*2     =    262,144  @ 77,594,624
    //   h1    : 128*1024*2     =    262,144  @ 77,856,768
    //   flags : 32768*4        =    131,072  @ 78,118,912  -> 78,249,984 total
    unsigned short* WT  = (unsigned short*)(ws);
    unsigned short* xb  = (unsigned short*)(ws + 10485760);
    unsigned short* h0  = (unsigned short*)(ws + 77594624);
    unsigned short* h1  = (unsigned short*)(ws + 77856768);
    unsigned int* flags = (unsigned int*)(ws + 78118912);

    hipLaunchKernelGGL(prep_wt, dim3(KTOT / 64, NGATE / 64), dim3(256), 0, stream,
                       Wx, Wh, WT);
    hipLaunchKernelGGL(prep_x, dim3(1024), dim3(256), 0, stream, x, xb, h0, flags);

    hipLaunchKernelGGL(lstm_persist, dim3(256), dim3(256), 0, stream,
                       xb, WT, h0, h1, flags, bias);

    // 1024 steps -> final h lands in h0
    hipLaunchKernelGGL(final_fc, dim3(128), dim3(256), 0, stream, h0, Wfc, bfc, out);
}